// Round 1
// baseline (7973.692 us; speedup 1.0000x reference)
//
#include <hip/hip_runtime.h>

#define BATCH   262144
#define LATENT  100
#define HDIM    64
#define SEQ_LEN 30
#define DT      0.03f

__device__ __forceinline__ float sigm(float x) {
    // 1/(1+e^-x); e^-x -> inf gives 0, e^-x -> 0 gives 1: safe at extremes
    return __fdividef(1.0f, 1.0f + __expf(-x));
}
__device__ __forceinline__ float tanh_f(float x) {
    // sign-safe tanh: e = exp(-2|x|) in (0,1], no overflow/NaN
    float ax = fabsf(x);
    float e  = __expf(-2.0f * ax);
    float t  = __fdividef(1.0f - e, 1.0f + e);
    return copysignf(t, x);
}

// Fold W_emb/b_emb into W_ih: Weff[256][4], beff[256] into ws.
__global__ void prep_kernel(const float* __restrict__ W_emb,
                            const float* __restrict__ b_emb,
                            const float* __restrict__ W_ih,
                            const float* __restrict__ b_ih,
                            const float* __restrict__ b_hh,
                            float* __restrict__ ws) {
    int r = threadIdx.x;  // 0..255 (gate row)
    float a0 = 0.f, a1 = 0.f, a2 = 0.f, a3 = 0.f;
    float bb = b_ih[r] + b_hh[r];
    for (int k = 0; k < HDIM; ++k) {
        float w = W_ih[r * HDIM + k];
        a0 = fmaf(w, W_emb[k * 4 + 0], a0);
        a1 = fmaf(w, W_emb[k * 4 + 1], a1);
        a2 = fmaf(w, W_emb[k * 4 + 2], a2);
        a3 = fmaf(w, W_emb[k * 4 + 3], a3);
        bb = fmaf(w, b_emb[k], bb);
    }
    ws[r * 4 + 0] = a0;
    ws[r * 4 + 1] = a1;
    ws[r * 4 + 2] = a2;
    ws[r * 4 + 3] = a3;
    ws[1024 + r]  = bb;
}

__launch_bounds__(256, 2)
__global__ void rollout_kernel(const float* __restrict__ z,
                               const float* __restrict__ init_state,
                               const float* __restrict__ W_hh,
                               const float* __restrict__ W_ctrl,
                               const float* __restrict__ b_ctrl,
                               const float* __restrict__ W_init,
                               const float* __restrict__ b_init,
                               const float* __restrict__ ws,
                               float* __restrict__ out) {
    const int b = blockIdx.x * 256 + threadIdx.x;
    if (b >= BATCH) return;

    const float* __restrict__ Weff = ws;          // [256][4]
    const float* __restrict__ beff = ws + 1024;   // [256]

    float h[HDIM], c[HDIM];

    // ---- h0 = z @ W_init.T + b_init ; c0 = h0 ----
    #pragma unroll
    for (int j = 0; j < HDIM; ++j) h[j] = b_init[j];

    const float4* z4 = (const float4*)z;  // 25 float4 per row (100 f32, 16B-aligned)
    #pragma unroll 1
    for (int kk = 0; kk < LATENT / 4; ++kk) {
        float4 zv = z4[(size_t)b * (LATENT / 4) + kk];
        #pragma unroll
        for (int j = 0; j < HDIM; ++j) {
            h[j] = fmaf(zv.x, W_init[j * LATENT + kk * 4 + 0], h[j]);
            h[j] = fmaf(zv.y, W_init[j * LATENT + kk * 4 + 1], h[j]);
            h[j] = fmaf(zv.z, W_init[j * LATENT + kk * 4 + 2], h[j]);
            h[j] = fmaf(zv.w, W_init[j * LATENT + kk * 4 + 3], h[j]);
        }
    }
    #pragma unroll
    for (int j = 0; j < HDIM; ++j) c[j] = h[j];

    float4 s = ((const float4*)init_state)[b];  // x, y, psi, v
    float4* out4 = (float4*)out;

    #pragma unroll 1
    for (int t = 0; t < SEQ_LEN; ++t) {
        float hn[HDIM];
        #pragma unroll
        for (int j = 0; j < HDIM; ++j) {
            float ai = beff[j];
            float af = beff[64 + j];
            float ag = beff[128 + j];
            float ao = beff[192 + j];
            // state (4-dim) contribution via folded weights
            ai = fmaf(Weff[j * 4 + 0], s.x, ai);
            ai = fmaf(Weff[j * 4 + 1], s.y, ai);
            ai = fmaf(Weff[j * 4 + 2], s.z, ai);
            ai = fmaf(Weff[j * 4 + 3], s.w, ai);
            af = fmaf(Weff[(64 + j) * 4 + 0], s.x, af);
            af = fmaf(Weff[(64 + j) * 4 + 1], s.y, af);
            af = fmaf(Weff[(64 + j) * 4 + 2], s.z, af);
            af = fmaf(Weff[(64 + j) * 4 + 3], s.w, af);
            ag = fmaf(Weff[(128 + j) * 4 + 0], s.x, ag);
            ag = fmaf(Weff[(128 + j) * 4 + 1], s.y, ag);
            ag = fmaf(Weff[(128 + j) * 4 + 2], s.z, ag);
            ag = fmaf(Weff[(128 + j) * 4 + 3], s.w, ag);
            ao = fmaf(Weff[(192 + j) * 4 + 0], s.x, ao);
            ao = fmaf(Weff[(192 + j) * 4 + 1], s.y, ao);
            ao = fmaf(Weff[(192 + j) * 4 + 2], s.z, ao);
            ao = fmaf(Weff[(192 + j) * 4 + 3], s.w, ao);
            // hidden contribution: 4 independent FMA chains over k
            #pragma unroll
            for (int k = 0; k < HDIM; ++k) {
                float hk = h[k];
                ai = fmaf(W_hh[(0 * 64 + j) * HDIM + k], hk, ai);
                af = fmaf(W_hh[(1 * 64 + j) * HDIM + k], hk, af);
                ag = fmaf(W_hh[(2 * 64 + j) * HDIM + k], hk, ag);
                ao = fmaf(W_hh[(3 * 64 + j) * HDIM + k], hk, ao);
            }
            float ig = sigm(ai);
            float fg = sigm(af);
            float gg = tanh_f(ag);
            float og = sigm(ao);
            float cj = fmaf(fg, c[j], ig * gg);
            c[j]  = cj;
            hn[j] = og * tanh_f(cj);
        }

        // control = hn @ W_ctrl.T + b_ctrl
        float ped = b_ctrl[0];
        float str = b_ctrl[1];
        #pragma unroll
        for (int k = 0; k < HDIM; ++k) {
            ped = fmaf(W_ctrl[k], hn[k], ped);
            str = fmaf(W_ctrl[64 + k], hn[k], str);
        }

        // plant (psi/v read BEFORE update)
        float beta = fminf(0.5f, fmaxf(-0.5f, str));
        float v1   = fminf(10.0f, fmaxf(0.0f, fmaf(ped, DT, s.w)));
        float cpsi = __cosf(s.z);
        float spsi = __sinf(s.z);
        float tb   = __fdividef(__sinf(beta), __cosf(beta));
        float psid = fminf(1.57f, fmaxf(-1.57f, s.w * tb * 0.4f));
        s.x = fmaf(v1 * cpsi, DT, s.x);
        s.y = fmaf(v1 * spsi, DT, s.y);
        s.z = fmaf(psid, DT, s.z);
        s.w = v1;

        out4[(size_t)b * SEQ_LEN + t] = s;

        #pragma unroll
        for (int j = 0; j < HDIM; ++j) h[j] = hn[j];
    }
}

extern "C" void kernel_launch(void* const* d_in, const int* in_sizes, int n_in,
                              void* d_out, int out_size, void* d_ws, size_t ws_size,
                              hipStream_t stream) {
    const float* z          = (const float*)d_in[0];
    const float* init_state = (const float*)d_in[1];
    const float* W_emb      = (const float*)d_in[2];
    const float* b_emb      = (const float*)d_in[3];
    const float* W_ih       = (const float*)d_in[4];
    const float* W_hh       = (const float*)d_in[5];
    const float* b_ih       = (const float*)d_in[6];
    const float* b_hh       = (const float*)d_in[7];
    const float* W_ctrl     = (const float*)d_in[8];
    const float* b_ctrl     = (const float*)d_in[9];
    const float* W_init     = (const float*)d_in[10];
    const float* b_init     = (const float*)d_in[11];
    float* out = (float*)d_out;
    float* ws  = (float*)d_ws;  // [0..1023] Weff, [1024..1279] beff

    prep_kernel<<<1, 256, 0, stream>>>(W_emb, b_emb, W_ih, b_ih, b_hh, ws);
    rollout_kernel<<<BATCH / 256, 256, 0, stream>>>(
        z, init_state, W_hh, W_ctrl, b_ctrl, W_init, b_init, ws, out);
}